// Round 6
// baseline (97.769 us; speedup 1.0000x reference)
//
#include <hip/hip_runtime.h>

typedef unsigned long long ull;

#define QN 32768
#define GN 64
#define BSN 16
#define KM 4
#define INF __builtin_inff()

// ---------------- main two-kernel path ----------------
#define GPB 8                  // gt boxes per block
#define NL  (GPB * 2)          // 16 lists (pred/anchor per gt)
#define NT  1024
#define NW  (NT / 64)
#define QS  4                  // q-split factor
#define QC  (QN / QS)          // 8192 q per block
#define BUFCAP 128
#define NB1 (BSN * 8 * QS)     // 512 blocks
#define WS_NEED ((size_t)NB1 * NL * KM * sizeof(ull))   // 256 KB

__device__ __forceinline__ float bcast(float x) {
    return __uint_as_float(__builtin_amdgcn_readfirstlane(__float_as_uint(x)));
}

// a <- lowest-4 of merge(a,b), both ascending-sorted float[4]. 12 f32 minmax.
__device__ __forceinline__ void merge4f(float* a, const float* b) {
    float m0 = fminf(a[0], b[3]);
    float m1 = fminf(a[1], b[2]);
    float m2 = fminf(a[2], b[1]);
    float m3 = fminf(a[3], b[0]);
    float x0 = fminf(m0, m2), x2 = fmaxf(m0, m2);
    float x1 = fminf(m1, m3), x3 = fmaxf(m1, m3);
    a[0] = fminf(x0, x1); a[1] = fmaxf(x0, x1);
    a[2] = fminf(x2, x3); a[3] = fmaxf(x2, x3);
}

// branchy sorted-insert of kk into descending... (r0<=r1<=r2<=r3 ascending)
__device__ __forceinline__ void ins_u64(ull* r, ull kk) {
    if (kk < r[3]) {
        r[3] = kk; ull t;
        if (r[3] < r[2]) { t = r[2]; r[2] = r[3]; r[3] = t; }
        if (r[2] < r[1]) { t = r[1]; r[1] = r[2]; r[2] = t; }
        if (r[1] < r[0]) { t = r[0]; r[0] = r[1]; r[1] = t; }
    }
}

__global__ __launch_bounds__(NT, 8) void matcher_scan(
    const float4* __restrict__ pred, const float4* __restrict__ anc,
    const float4* __restrict__ gt, ull* __restrict__ ws)
{
    __shared__ float ws4[NL][NW][KM];   // per-wave top-4 of thread minima
    __shared__ float Ts[NL];
    __shared__ int   cnt[NL];
    __shared__ ull   buf[NL][BUFCAP];

    // XCD remap (bijective, 512 % 8 == 0): each XCD gets 64 consecutive logical
    // blocks = 2 whole batches -> 2 MB working set fits its private 4 MB L2.
    int L  = ((blockIdx.x & 7) << 6) | (blockIdx.x >> 3);
    int b  = L >> 5;           // 0..15
    int gc = (L >> 2) & 7;     // 0..7
    int qs = L & 3;            // 0..3
    int tid = threadIdx.x;

    // gt chunk cxcywh -> SGPRs (block-uniform): zero VGPR cost in inner loop
    float gx[GPB], gy[GPB], gw[GPB], gh[GPB];
#pragma unroll
    for (int j = 0; j < GPB; ++j) {
        float4 gb = gt[b * GN + gc * GPB + j];
        gx[j] = bcast((gb.x + gb.z) * 0.5f);
        gy[j] = bcast((gb.y + gb.w) * 0.5f);
        gw[j] = bcast(gb.z - gb.x);
        gh[j] = bcast(gb.w - gb.y);
    }

    const float4* pq = pred + (size_t)b * QN + qs * QC;
    const float4* aq = anc  + (size_t)b * QN + qs * QC;

    // ---- phase A: per-thread running min cost per list ----
    float mn[NL];
#pragma unroll
    for (int l = 0; l < NL; ++l) mn[l] = INF;

    for (int it = 0; it < QC; it += 2 * NT) {
        float4 p0 = pq[it + tid],      a0 = aq[it + tid];
        float4 p1 = pq[it + NT + tid], a1 = aq[it + NT + tid];
        {
            float pcx=(p0.x+p0.z)*0.5f, pcy=(p0.y+p0.w)*0.5f, pw=p0.z-p0.x, ph=p0.w-p0.y;
            float acx=(a0.x+a0.z)*0.5f, acy=(a0.y+a0.w)*0.5f, aw=a0.z-a0.x, ah=a0.w-a0.y;
#pragma unroll
            for (int j = 0; j < GPB; ++j) {
                float cb = ((fabsf(pcx-gx[j])+fabsf(pcy-gy[j]))+fabsf(pw-gw[j]))+fabsf(ph-gh[j]);
                mn[2*j]   = fminf(mn[2*j],   cb);
                float ca = ((fabsf(acx-gx[j])+fabsf(acy-gy[j]))+fabsf(aw-gw[j]))+fabsf(ah-gh[j]);
                mn[2*j+1] = fminf(mn[2*j+1], ca);
            }
        }
        {
            float pcx=(p1.x+p1.z)*0.5f, pcy=(p1.y+p1.w)*0.5f, pw=p1.z-p1.x, ph=p1.w-p1.y;
            float acx=(a1.x+a1.z)*0.5f, acy=(a1.y+a1.w)*0.5f, aw=a1.z-a1.x, ah=a1.w-a1.y;
#pragma unroll
            for (int j = 0; j < GPB; ++j) {
                float cb = ((fabsf(pcx-gx[j])+fabsf(pcy-gy[j]))+fabsf(pw-gw[j]))+fabsf(ph-gh[j]);
                mn[2*j]   = fminf(mn[2*j],   cb);
                float ca = ((fabsf(acx-gx[j])+fabsf(acy-gy[j]))+fabsf(aw-gw[j]))+fabsf(ah-gh[j]);
                mn[2*j+1] = fminf(mn[2*j+1], ca);
            }
        }
    }

    // threshold T[l] = 4th-smallest of the 1024 per-thread minima (>= true v4,
    // since a thread holding >=2 of the top-4 only pushes its min's rank down).
    // Butterfly in 4-list tranches to cap VGPR pressure (<64 for 2 blocks/CU).
    int lane = tid & 63, wv = tid >> 6;
#pragma unroll
    for (int tr = 0; tr < 4; ++tr) {
        float m4[4][KM];
#pragma unroll
        for (int tl = 0; tl < 4; ++tl) {
            m4[tl][0] = mn[tr*4+tl]; m4[tl][1] = INF; m4[tl][2] = INF; m4[tl][3] = INF;
        }
#pragma unroll
        for (int off = 1; off < 64; off <<= 1) {
#pragma unroll
            for (int tl = 0; tl < 4; ++tl) {
                float bb[KM];
#pragma unroll
                for (int s = 0; s < KM; ++s) bb[s] = __shfl_xor(m4[tl][s], off, 64);
                merge4f(m4[tl], bb);
            }
        }
        if (lane == 0)
#pragma unroll
            for (int tl = 0; tl < 4; ++tl)
#pragma unroll
                for (int s = 0; s < KM; ++s) ws4[tr*4+tl][wv][s] = m4[tl][s];
    }
    if (tid < NL) cnt[tid] = 0;
    __syncthreads();

    if (tid < NL) {
        float r[KM];
#pragma unroll
        for (int s = 0; s < KM; ++s) r[s] = ws4[tid][0][s];
        for (int w = 1; w < NW; ++w) merge4f(r, ws4[tid][w]);
        Ts[tid] = r[3];
    }
    __syncthreads();

    float T[NL];
#pragma unroll
    for (int l = 0; l < NL; ++l) T[l] = bcast(Ts[l]);   // SGPRs

    // ---- phase B: rescan (L2-hot), collect (cost,idx) keys with cost <= T ----
    // qualifying q's come only from threads whose min <= T (<=4 + ties), each
    // holding <= 8 q -> count <= ~32+ties << BUFCAP.
    for (int it = 0; it < QC; it += 2 * NT) {
        float4 p0 = pq[it + tid],      a0 = aq[it + tid];
        float4 p1 = pq[it + NT + tid], a1 = aq[it + NT + tid];
#pragma unroll
        for (int u = 0; u < 2; ++u) {
            float4 p = u ? p1 : p0;
            float4 a = u ? a1 : a0;
            int qg = qs * QC + it + u * NT + tid;   // global q index, 15 bits
            float pcx=(p.x+p.z)*0.5f, pcy=(p.y+p.w)*0.5f, pw=p.z-p.x, ph=p.w-p.y;
            float acx=(a.x+a.z)*0.5f, acy=(a.y+a.w)*0.5f, aw=a.z-a.x, ah=a.w-a.y;
#pragma unroll
            for (int j = 0; j < GPB; ++j) {
                float cb = ((fabsf(pcx-gx[j])+fabsf(pcy-gy[j]))+fabsf(pw-gw[j]))+fabsf(ph-gh[j]);
                if (cb <= T[2*j]) {
                    int s = atomicAdd(&cnt[2*j], 1);
                    if (s < BUFCAP)
                        buf[2*j][s] = (((ull)__float_as_uint(cb)) << 15) | (ull)(unsigned)qg;
                }
                float ca = ((fabsf(acx-gx[j])+fabsf(acy-gy[j]))+fabsf(aw-gw[j]))+fabsf(ah-gh[j]);
                if (ca <= T[2*j+1]) {
                    int s = atomicAdd(&cnt[2*j+1], 1);
                    if (s < BUFCAP)
                        buf[2*j+1][s] = (((ull)__float_as_uint(ca)) << 15) | (ull)(unsigned)qg;
                }
            }
        }
    }
    __syncthreads();

    // exact lexicographic top-4 of collected keys -> ws[L][l][0..3]
    if (tid < NL) {
        int l = tid;
        int n = cnt[l]; if (n > BUFCAP) n = BUFCAP;
        ull r[KM] = { ~0ull, ~0ull, ~0ull, ~0ull };
        for (int i = 0; i < n; ++i) ins_u64(r, buf[l][i]);
        ull* w = ws + ((size_t)L * NL + l) * KM;
#pragma unroll
        for (int s = 0; s < KM; ++s) w[s] = r[s];
    }
}

__global__ __launch_bounds__(1024) void matcher_merge(
    const ull* __restrict__ ws, int* __restrict__ out)
{
    int t = blockIdx.x * 1024 + threadIdx.x;
    if (t >= BSN * 8 * NL) return;          // 2048 tasks
    int b  = t >> 7;
    int gc = (t >> 4) & 7;
    int l  = t & 15;

    ull r[KM];
    const ull* w0 = ws + ((size_t)(((b * 8 + gc) * QS + 0) * NL + l)) * KM;
#pragma unroll
    for (int s = 0; s < KM; ++s) r[s] = w0[s];
#pragma unroll
    for (int q = 1; q < QS; ++q) {
        const ull* w = ws + ((size_t)(((b * 8 + gc) * QS + q) * NL + l)) * KM;
#pragma unroll
        for (int s = 0; s < KM; ++s) ins_u64(r, w[s]);
    }

    int gl = l >> 1, type = l & 1;
    int g = gc * GPB + gl;
    int base = b * (2 * KM * GN);
    int* out_j = out + BSN * 2 * KM * GN;
#pragma unroll
    for (int m = 0; m < KM; ++m) {
        int qi = (int)(r[m] & 32767ull);
        // idx_i layout: [b, m, type, g] -> b*512 + m*128 + type*64 + g
        int pos = base + m * (2 * GN) + type * GN + g;
        out[pos]   = qi;
        out_j[pos] = g;
    }
}

// ---------------- fallback (round-5 proven): used only if ws too small ----------------
__global__ __launch_bounds__(1024) void matcher_single(
    const float4* __restrict__ pred, const float4* __restrict__ anc,
    const float4* __restrict__ gt, int* __restrict__ out)
{
    __shared__ float fws4[8][16][KM];
    __shared__ float fTs[8];
    __shared__ int   fcnt[8];
    __shared__ ull   fbuf[8][64];

    int bid = blockIdx.x;
    int xcd = bid & 7;
    int k   = bid >> 3;
    int b   = (xcd << 1) | (k & 1);
    int gc  = k >> 1;
    int tid = threadIdx.x;

    float gx[4], gy[4], gw[4], gh[4];
#pragma unroll
    for (int j = 0; j < 4; ++j) {
        float4 gb = gt[b * GN + gc * 4 + j];
        gx[j] = (gb.x + gb.z) * 0.5f; gy[j] = (gb.y + gb.w) * 0.5f;
        gw[j] = gb.z - gb.x;          gh[j] = gb.w - gb.y;
    }
    const float4* pb = pred + (size_t)b * QN;
    const float4* ab = anc  + (size_t)b * QN;

    float mn[8];
#pragma unroll
    for (int l = 0; l < 8; ++l) mn[l] = INF;

    for (int q0 = tid; q0 < QN; q0 += 1024) {
        float4 p = pb[q0], a = ab[q0];
        float pcx=(p.x+p.z)*0.5f, pcy=(p.y+p.w)*0.5f, pw=p.z-p.x, ph=p.w-p.y;
        float acx=(a.x+a.z)*0.5f, acy=(a.y+a.w)*0.5f, aw=a.z-a.x, ah=a.w-a.y;
#pragma unroll
        for (int j = 0; j < 4; ++j) {
            mn[2*j]   = fminf(mn[2*j],   ((fabsf(pcx-gx[j])+fabsf(pcy-gy[j]))+fabsf(pw-gw[j]))+fabsf(ph-gh[j]));
            mn[2*j+1] = fminf(mn[2*j+1], ((fabsf(acx-gx[j])+fabsf(acy-gy[j]))+fabsf(aw-gw[j]))+fabsf(ah-gh[j]));
        }
    }

    float m4[8][KM];
#pragma unroll
    for (int l = 0; l < 8; ++l) { m4[l][0]=mn[l]; m4[l][1]=INF; m4[l][2]=INF; m4[l][3]=INF; }
#pragma unroll
    for (int off = 1; off < 64; off <<= 1) {
#pragma unroll
        for (int l = 0; l < 8; ++l) {
            float bb[KM];
#pragma unroll
            for (int s = 0; s < KM; ++s) bb[s] = __shfl_xor(m4[l][s], off, 64);
            merge4f(m4[l], bb);
        }
    }
    int lane = tid & 63, wv = tid >> 6;
    if (lane == 0)
#pragma unroll
        for (int l = 0; l < 8; ++l)
#pragma unroll
            for (int s = 0; s < KM; ++s) fws4[l][wv][s] = m4[l][s];
    if (tid < 8) fcnt[tid] = 0;
    __syncthreads();
    if (tid < 8) {
        float r[KM];
#pragma unroll
        for (int s = 0; s < KM; ++s) r[s] = fws4[tid][0][s];
        for (int w = 1; w < 16; ++w) merge4f(r, fws4[tid][w]);
        fTs[tid] = r[3];
    }
    __syncthreads();
    float T[8];
#pragma unroll
    for (int l = 0; l < 8; ++l) T[l] = fTs[l];

    for (int q0 = tid; q0 < QN; q0 += 1024) {
        float4 p = pb[q0], a = ab[q0];
        float pcx=(p.x+p.z)*0.5f, pcy=(p.y+p.w)*0.5f, pw=p.z-p.x, ph=p.w-p.y;
        float acx=(a.x+a.z)*0.5f, acy=(a.y+a.w)*0.5f, aw=a.z-a.x, ah=a.w-a.y;
#pragma unroll
        for (int j = 0; j < 4; ++j) {
            float cb = ((fabsf(pcx-gx[j])+fabsf(pcy-gy[j]))+fabsf(pw-gw[j]))+fabsf(ph-gh[j]);
            if (cb <= T[2*j]) {
                int s = atomicAdd(&fcnt[2*j], 1);
                if (s < 64) fbuf[2*j][s] = (((ull)__float_as_uint(cb)) << 15) | (ull)(unsigned)q0;
            }
            float ca = ((fabsf(acx-gx[j])+fabsf(acy-gy[j]))+fabsf(aw-gw[j]))+fabsf(ah-gh[j]);
            if (ca <= T[2*j+1]) {
                int s = atomicAdd(&fcnt[2*j+1], 1);
                if (s < 64) fbuf[2*j+1][s] = (((ull)__float_as_uint(ca)) << 15) | (ull)(unsigned)q0;
            }
        }
    }
    __syncthreads();

    if (tid < 8) {
        int l = tid, n = fcnt[l]; if (n > 64) n = 64;
        ull r[KM] = { ~0ull, ~0ull, ~0ull, ~0ull };
        for (int i = 0; i < n; ++i) ins_u64(r, fbuf[l][i]);
        int gl = l >> 1, type = l & 1;
        int g = gc * 4 + gl;
        int base = b * (2 * KM * GN);
        int* out_j = out + BSN * 2 * KM * GN;
#pragma unroll
        for (int m = 0; m < KM; ++m) {
            int qi = (int)(r[m] & 32767ull);
            int pos = base + m * (2 * GN) + type * GN + g;
            out[pos]   = qi;
            out_j[pos] = g;
        }
    }
}

extern "C" void kernel_launch(void* const* d_in, const int* in_sizes, int n_in,
                              void* d_out, int out_size, void* d_ws, size_t ws_size,
                              hipStream_t stream) {
    const float4* pred = (const float4*)d_in[0];
    const float4* anc  = (const float4*)d_in[1];
    const float4* gt   = (const float4*)d_in[2];
    int* out = (int*)d_out;

    if (ws_size >= WS_NEED) {
        ull* ws = (ull*)d_ws;
        matcher_scan<<<NB1, NT, 0, stream>>>(pred, anc, gt, ws);
        matcher_merge<<<2, 1024, 0, stream>>>(ws, out);
    } else {
        matcher_single<<<256, 1024, 0, stream>>>(pred, anc, gt, out);
    }
}

// Round 7
// 63.060 us; speedup vs baseline: 1.5504x; 1.5504x over previous
//
#include <hip/hip_runtime.h>

typedef unsigned long long ull;

#define QN 32768
#define GN 64
#define BSN 16
#define KM 4
#define INF __builtin_inff()

// ---- main path: type-split scan (512 blocks) + tiny merge ----
#define GPB 8                   // gt boxes per block
#define NL  GPB                 // 8 lists (ONE type per block)
#define NT  1024
#define NW  (NT / 64)
#define QS  2                   // q-split
#define QC  (QN / QS)           // 16384 q per block
#define NB  (BSN * 2 * 8 * QS)  // 512 blocks
#define BUFCAP 128
#define WS_NEED ((size_t)NB * NL * KM * sizeof(ull))   // 128 KB

__device__ __forceinline__ float bcast(float x) {
    return __uint_as_float(__builtin_amdgcn_readfirstlane(__float_as_uint(x)));
}

// a <- lowest-4 of merge(a,b), both ascending-sorted float[4]. 12 f32 minmax.
__device__ __forceinline__ void merge4f(float* a, const float* b) {
    float m0 = fminf(a[0], b[3]);
    float m1 = fminf(a[1], b[2]);
    float m2 = fminf(a[2], b[1]);
    float m3 = fminf(a[3], b[0]);
    float x0 = fminf(m0, m2), x2 = fmaxf(m0, m2);
    float x1 = fminf(m1, m3), x3 = fmaxf(m1, m3);
    a[0] = fminf(x0, x1); a[1] = fmaxf(x0, x1);
    a[2] = fminf(x2, x3); a[3] = fmaxf(x2, x3);
}

// sorted-insert (ascending r[0..3]) of kk, keep 4 smallest
__device__ __forceinline__ void ins_u64(ull* r, ull kk) {
    if (kk < r[3]) {
        r[3] = kk; ull t;
        if (r[3] < r[2]) { t = r[2]; r[2] = r[3]; r[3] = t; }
        if (r[2] < r[1]) { t = r[1]; r[1] = r[2]; r[2] = t; }
        if (r[1] < r[0]) { t = r[0]; r[0] = r[1]; r[1] = t; }
    }
}

__global__ __launch_bounds__(NT) void matcher_scan(
    const float4* __restrict__ pred, const float4* __restrict__ anc,
    const float4* __restrict__ gt, ull* __restrict__ ws)
{
    __shared__ float ws4[NL][NW][KM];
    __shared__ float Ts[NL];
    __shared__ int   cnt[NL];
    __shared__ ull   buf[NL][BUFCAP];

    // XCD remap (bijective, 512%8==0): 64 consecutive logical blocks per XCD
    // = 2 whole batches (both tensors) -> 2 MB working set per XCD L2.
    int L    = ((blockIdx.x & 7) << 6) | (blockIdx.x >> 3);
    int b    = L >> 5;            // 0..15
    int type = (L >> 4) & 1;      // 0=pred, 1=anchor
    int gc   = (L >> 1) & 7;      // 0..7
    int qs   = L & 1;             // 0..1
    int tid  = threadIdx.x;

    // gt chunk cxcywh -> SGPRs (block-uniform)
    float gx[GPB], gy[GPB], gw[GPB], gh[GPB];
#pragma unroll
    for (int j = 0; j < GPB; ++j) {
        float4 gb = gt[b * GN + gc * GPB + j];
        gx[j] = bcast((gb.x + gb.z) * 0.5f);
        gy[j] = bcast((gb.y + gb.w) * 0.5f);
        gw[j] = bcast(gb.z - gb.x);
        gh[j] = bcast(gb.w - gb.y);
    }

    const float4* src = (type ? anc : pred) + (size_t)b * QN + qs * QC;

    // ---- phase A: per-thread running min cost per list ----
    float mn[NL];
#pragma unroll
    for (int l = 0; l < NL; ++l) mn[l] = INF;

    for (int it = 0; it < QC; it += 2 * NT) {
        float4 p0 = src[it + tid];
        float4 p1 = src[it + NT + tid];
#pragma unroll
        for (int u = 0; u < 2; ++u) {
            float4 p = u ? p1 : p0;
            float cx = (p.x + p.z) * 0.5f, cy = (p.y + p.w) * 0.5f;
            float w  = p.z - p.x,          h  = p.w - p.y;
#pragma unroll
            for (int j = 0; j < GPB; ++j) {
                // reference op order: ((|dcx|+|dcy|)+|dw|)+|dh|
                float c = ((fabsf(cx - gx[j]) + fabsf(cy - gy[j]))
                           + fabsf(w - gw[j])) + fabsf(h - gh[j]);
                mn[j] = fminf(mn[j], c);
            }
        }
    }

    // T[l] = 4th-smallest of 1024 per-thread minima (>= true v4: a thread
    // holding >=2 of the top-4 only pushes its min's rank down, never up).
    float m4[NL][KM];
#pragma unroll
    for (int l = 0; l < NL; ++l) {
        m4[l][0] = mn[l]; m4[l][1] = INF; m4[l][2] = INF; m4[l][3] = INF;
    }
#pragma unroll
    for (int off = 1; off < 64; off <<= 1) {
#pragma unroll
        for (int l = 0; l < NL; ++l) {
            float bb[KM];
#pragma unroll
            for (int s = 0; s < KM; ++s) bb[s] = __shfl_xor(m4[l][s], off, 64);
            merge4f(m4[l], bb);
        }
    }
    int lane = tid & 63, wv = tid >> 6;
    if (lane == 0)
#pragma unroll
        for (int l = 0; l < NL; ++l)
#pragma unroll
            for (int s = 0; s < KM; ++s) ws4[l][wv][s] = m4[l][s];
    if (tid < NL) cnt[tid] = 0;
    __syncthreads();

    if (tid < NL) {
        float r[KM];
#pragma unroll
        for (int s = 0; s < KM; ++s) r[s] = ws4[tid][0][s];
        for (int w = 1; w < NW; ++w) merge4f(r, ws4[tid][w]);
        Ts[tid] = r[3];
    }
    __syncthreads();

    float T[NL];
#pragma unroll
    for (int l = 0; l < NL; ++l) T[l] = bcast(Ts[l]);   // SGPRs

    // ---- phase B: rescan (L2-hot), collect keys with cost <= T ----
    for (int it = 0; it < QC; it += 2 * NT) {
        float4 p0 = src[it + tid];
        float4 p1 = src[it + NT + tid];
#pragma unroll
        for (int u = 0; u < 2; ++u) {
            float4 p = u ? p1 : p0;
            int qg = qs * QC + it + u * NT + tid;    // global q, 15 bits
            float cx = (p.x + p.z) * 0.5f, cy = (p.y + p.w) * 0.5f;
            float w  = p.z - p.x,          h  = p.w - p.y;
            float c[NL];
            bool any = false;
#pragma unroll
            for (int j = 0; j < GPB; ++j) {
                c[j] = ((fabsf(cx - gx[j]) + fabsf(cy - gy[j]))
                        + fabsf(w - gw[j])) + fabsf(h - gh[j]);
                any = any || (c[j] <= T[j]);
            }
            if (__any(any)) {                 // rare at wave level (~6%)
#pragma unroll
                for (int j = 0; j < GPB; ++j) {
                    if (c[j] <= T[j]) {
                        int s = atomicAdd(&cnt[j], 1);
                        if (s < BUFCAP)
                            buf[j][s] = (((ull)__float_as_uint(c[j])) << 15)
                                        | (ull)(unsigned)qg;
                    }
                }
            }
        }
    }
    __syncthreads();

    // exact lexicographic top-4 of collected keys -> ws[L][l][0..3]
    if (tid < NL) {
        int l = tid;
        int n = cnt[l]; if (n > BUFCAP) n = BUFCAP;
        ull r[KM] = { ~0ull, ~0ull, ~0ull, ~0ull };
        for (int i = 0; i < n; ++i) ins_u64(r, buf[l][i]);
        ull* w = ws + ((size_t)L * NL + l) * KM;
#pragma unroll
        for (int s = 0; s < KM; ++s) w[s] = r[s];
    }
}

__global__ __launch_bounds__(256) void matcher_merge(
    const ull* __restrict__ ws, int* __restrict__ out)
{
    int t = blockIdx.x * 256 + threadIdx.x;
    if (t >= BSN * 2 * 8 * GPB) return;      // 2048 tasks
    int b    = t >> 7;
    int type = (t >> 6) & 1;
    int gc   = (t >> 3) & 7;
    int gl   = t & 7;

    ull r[KM];
    {
        int L0 = (b << 5) | (type << 4) | (gc << 1) | 0;
        const ull* w = ws + ((size_t)L0 * NL + gl) * KM;
#pragma unroll
        for (int s = 0; s < KM; ++s) r[s] = w[s];
    }
#pragma unroll
    for (int qs = 1; qs < QS; ++qs) {
        int L = (b << 5) | (type << 4) | (gc << 1) | qs;
        const ull* w = ws + ((size_t)L * NL + gl) * KM;
#pragma unroll
        for (int s = 0; s < KM; ++s) ins_u64(r, w[s]);
    }

    int g = gc * GPB + gl;
    int base = b * (2 * KM * GN);
    int* out_j = out + BSN * 2 * KM * GN;
#pragma unroll
    for (int m = 0; m < KM; ++m) {
        int qi = (int)(r[m] & 32767ull);
        // idx_i layout: [b, m, type, g] -> b*512 + m*128 + type*64 + g
        int pos = base + m * (2 * GN) + type * GN + g;
        out[pos]   = qi;
        out_j[pos] = g;
    }
}

// ---- fallback (round-5 proven) if ws is too small ----
__global__ __launch_bounds__(1024) void matcher_single(
    const float4* __restrict__ pred, const float4* __restrict__ anc,
    const float4* __restrict__ gt, int* __restrict__ out)
{
    __shared__ float fws4[8][16][KM];
    __shared__ float fTs[8];
    __shared__ int   fcnt[8];
    __shared__ ull   fbuf[8][64];

    int bid = blockIdx.x;
    int xcd = bid & 7;
    int k   = bid >> 3;
    int b   = (xcd << 1) | (k & 1);
    int gc  = k >> 1;
    int tid = threadIdx.x;

    float gx[4], gy[4], gw[4], gh[4];
#pragma unroll
    for (int j = 0; j < 4; ++j) {
        float4 gb = gt[b * GN + gc * 4 + j];
        gx[j] = (gb.x + gb.z) * 0.5f; gy[j] = (gb.y + gb.w) * 0.5f;
        gw[j] = gb.z - gb.x;          gh[j] = gb.w - gb.y;
    }
    const float4* pb = pred + (size_t)b * QN;
    const float4* ab = anc  + (size_t)b * QN;

    float mn[8];
#pragma unroll
    for (int l = 0; l < 8; ++l) mn[l] = INF;

    for (int q0 = tid; q0 < QN; q0 += 1024) {
        float4 p = pb[q0], a = ab[q0];
        float pcx=(p.x+p.z)*0.5f, pcy=(p.y+p.w)*0.5f, pw=p.z-p.x, ph=p.w-p.y;
        float acx=(a.x+a.z)*0.5f, acy=(a.y+a.w)*0.5f, aw=a.z-a.x, ah=a.w-a.y;
#pragma unroll
        for (int j = 0; j < 4; ++j) {
            mn[2*j]   = fminf(mn[2*j],   ((fabsf(pcx-gx[j])+fabsf(pcy-gy[j]))+fabsf(pw-gw[j]))+fabsf(ph-gh[j]));
            mn[2*j+1] = fminf(mn[2*j+1], ((fabsf(acx-gx[j])+fabsf(acy-gy[j]))+fabsf(aw-gw[j]))+fabsf(ah-gh[j]));
        }
    }

    float m4[8][KM];
#pragma unroll
    for (int l = 0; l < 8; ++l) { m4[l][0]=mn[l]; m4[l][1]=INF; m4[l][2]=INF; m4[l][3]=INF; }
#pragma unroll
    for (int off = 1; off < 64; off <<= 1) {
#pragma unroll
        for (int l = 0; l < 8; ++l) {
            float bb[KM];
#pragma unroll
            for (int s = 0; s < KM; ++s) bb[s] = __shfl_xor(m4[l][s], off, 64);
            merge4f(m4[l], bb);
        }
    }
    int lane = tid & 63, wv = tid >> 6;
    if (lane == 0)
#pragma unroll
        for (int l = 0; l < 8; ++l)
#pragma unroll
            for (int s = 0; s < KM; ++s) fws4[l][wv][s] = m4[l][s];
    if (tid < 8) fcnt[tid] = 0;
    __syncthreads();
    if (tid < 8) {
        float r[KM];
#pragma unroll
        for (int s = 0; s < KM; ++s) r[s] = fws4[tid][0][s];
        for (int w = 1; w < 16; ++w) merge4f(r, fws4[tid][w]);
        fTs[tid] = r[3];
    }
    __syncthreads();
    float T[8];
#pragma unroll
    for (int l = 0; l < 8; ++l) T[l] = fTs[l];

    for (int q0 = tid; q0 < QN; q0 += 1024) {
        float4 p = pb[q0], a = ab[q0];
        float pcx=(p.x+p.z)*0.5f, pcy=(p.y+p.w)*0.5f, pw=p.z-p.x, ph=p.w-p.y;
        float acx=(a.x+a.z)*0.5f, acy=(a.y+a.w)*0.5f, aw=a.z-a.x, ah=a.w-a.y;
#pragma unroll
        for (int j = 0; j < 4; ++j) {
            float cb = ((fabsf(pcx-gx[j])+fabsf(pcy-gy[j]))+fabsf(pw-gw[j]))+fabsf(ph-gh[j]);
            if (cb <= T[2*j]) {
                int s = atomicAdd(&fcnt[2*j], 1);
                if (s < 64) fbuf[2*j][s] = (((ull)__float_as_uint(cb)) << 15) | (ull)(unsigned)q0;
            }
            float ca = ((fabsf(acx-gx[j])+fabsf(acy-gy[j]))+fabsf(aw-gw[j]))+fabsf(ah-gh[j]);
            if (ca <= T[2*j+1]) {
                int s = atomicAdd(&fcnt[2*j+1], 1);
                if (s < 64) fbuf[2*j+1][s] = (((ull)__float_as_uint(ca)) << 15) | (ull)(unsigned)q0;
            }
        }
    }
    __syncthreads();

    if (tid < 8) {
        int l = tid, n = fcnt[l]; if (n > 64) n = 64;
        ull r[KM] = { ~0ull, ~0ull, ~0ull, ~0ull };
        for (int i = 0; i < n; ++i) ins_u64(r, fbuf[l][i]);
        int gl = l >> 1, type = l & 1;
        int g = gc * 4 + gl;
        int base = b * (2 * KM * GN);
        int* out_j = out + BSN * 2 * KM * GN;
#pragma unroll
        for (int m = 0; m < KM; ++m) {
            int qi = (int)(r[m] & 32767ull);
            int pos = base + m * (2 * GN) + type * GN + g;
            out[pos]   = qi;
            out_j[pos] = g;
        }
    }
}

extern "C" void kernel_launch(void* const* d_in, const int* in_sizes, int n_in,
                              void* d_out, int out_size, void* d_ws, size_t ws_size,
                              hipStream_t stream) {
    const float4* pred = (const float4*)d_in[0];
    const float4* anc  = (const float4*)d_in[1];
    const float4* gt   = (const float4*)d_in[2];
    int* out = (int*)d_out;

    if (ws_size >= WS_NEED) {
        ull* ws = (ull*)d_ws;
        matcher_scan<<<NB, NT, 0, stream>>>(pred, anc, gt, ws);
        matcher_merge<<<8, 256, 0, stream>>>(ws, out);
    } else {
        matcher_single<<<256, 1024, 0, stream>>>(pred, anc, gt, out);
    }
}

// Round 8
// 51.006 us; speedup vs baseline: 1.9168x; 1.2363x over previous
//
#include <hip/hip_runtime.h>

typedef unsigned long long ull;

#define QN 32768
#define GN 64
#define BSN 16
#define KM 4
#define INF __builtin_inff()

// ---- main path: 1024 blocks x 512 thr, subsampled threshold + collect ----
#define GPB 4                   // gt boxes per block (both types -> 8 lists)
#define NL  (GPB * 2)
#define NT  512
#define NW  (NT / 64)           // 8 waves = NL lists
#define QS  4                   // q-split
#define QC  (QN / QS)           // 8192 q per block
#define QPT (QC / NT)           // 16 q per thread
#define SUB 4                   // subsample iters/thread (1/4 of slice)
#define NB  (BSN * 16 * QS)     // 1024 blocks
#define BUFCAP 128
#define WS_NEED ((size_t)NB * NL * KM * sizeof(ull))   // 256 KB

__device__ __forceinline__ float bcast(float x) {
    return __uint_as_float(__builtin_amdgcn_readfirstlane(__float_as_uint(x)));
}

// a <- lowest-4 of merge(a,b), both ascending-sorted float[4]. 12 f32 minmax.
__device__ __forceinline__ void merge4f(float* a, const float* b) {
    float m0 = fminf(a[0], b[3]);
    float m1 = fminf(a[1], b[2]);
    float m2 = fminf(a[2], b[1]);
    float m3 = fminf(a[3], b[0]);
    float x0 = fminf(m0, m2), x2 = fmaxf(m0, m2);
    float x1 = fminf(m1, m3), x3 = fmaxf(m1, m3);
    a[0] = fminf(x0, x1); a[1] = fmaxf(x0, x1);
    a[2] = fminf(x2, x3); a[3] = fmaxf(x2, x3);
}

// branchy sorted-insert (ascending r[0..3]), keep 4 smallest values
__device__ __forceinline__ void insf(float* r, float v) {
    if (v < r[3]) {
        r[3] = v; float t;
        if (r[3] < r[2]) { t = r[2]; r[2] = r[3]; r[3] = t; }
        if (r[2] < r[1]) { t = r[1]; r[1] = r[2]; r[2] = t; }
        if (r[1] < r[0]) { t = r[0]; r[0] = r[1]; r[1] = t; }
    }
}

// sorted-insert (ascending r[0..3]) of u64 key, keep 4 smallest
__device__ __forceinline__ void ins_u64(ull* r, ull kk) {
    if (kk < r[3]) {
        r[3] = kk; ull t;
        if (r[3] < r[2]) { t = r[2]; r[2] = r[3]; r[3] = t; }
        if (r[2] < r[1]) { t = r[1]; r[1] = r[2]; r[2] = t; }
        if (r[1] < r[0]) { t = r[0]; r[0] = r[1]; r[1] = t; }
    }
}

__global__ __launch_bounds__(NT) void matcher_scan(
    const float4* __restrict__ pred, const float4* __restrict__ anc,
    const float4* __restrict__ gt, ull* __restrict__ ws)
{
    __shared__ float mnAll[NL][NT];    // 16 KB: per-thread subsample minima
    __shared__ float Ts[NL];
    __shared__ int   cnt[NL];
    __shared__ ull   buf[NL][BUFCAP];  // 8 KB

    // XCD remap (bijective, 1024%8==0): 128 consecutive logical blocks per
    // XCD = 2 whole batches (pred+anc = 2 MB) -> fits private 4 MB L2.
    int L   = ((blockIdx.x & 7) << 7) | (blockIdx.x >> 3);
    int b   = L >> 6;             // 0..15
    int gc  = (L >> 2) & 15;      // 0..15 (chunk of 4 gt)
    int qs  = L & 3;              // 0..3
    int tid = threadIdx.x;

    // gt chunk cxcywh -> SGPRs (block-uniform)
    float gx[GPB], gy[GPB], gw[GPB], gh[GPB];
#pragma unroll
    for (int j = 0; j < GPB; ++j) {
        float4 gb = gt[b * GN + gc * GPB + j];
        gx[j] = bcast((gb.x + gb.z) * 0.5f);
        gy[j] = bcast((gb.y + gb.w) * 0.5f);
        gw[j] = bcast(gb.z - gb.x);
        gh[j] = bcast(gb.w - gb.y);
    }

    const float4* pq = pred + (size_t)b * QN + qs * QC;
    const float4* aq = anc  + (size_t)b * QN + qs * QC;

    // ---- phase A (subsample 1/4): per-thread running min per list ----
    // T from a subset is >= 4th-smallest of the subset >= v4 of the slice,
    // so the phase-B filter {c <= T} still provably contains the top-4.
    float mn[NL];
#pragma unroll
    for (int l = 0; l < NL; ++l) mn[l] = INF;

#pragma unroll
    for (int it = 0; it < SUB; it += 2) {
        int o0 = it * NT + tid, o1 = (it + 1) * NT + tid;
        float4 p0 = pq[o0], a0 = aq[o0], p1 = pq[o1], a1 = aq[o1];
#pragma unroll
        for (int u = 0; u < 2; ++u) {
            float4 p = u ? p1 : p0;
            float4 a = u ? a1 : a0;
            float pcx=(p.x+p.z)*0.5f, pcy=(p.y+p.w)*0.5f, pw=p.z-p.x, ph=p.w-p.y;
            float acx=(a.x+a.z)*0.5f, acy=(a.y+a.w)*0.5f, aw=a.z-a.x, ah=a.w-a.y;
#pragma unroll
            for (int j = 0; j < GPB; ++j) {
                // reference op order: ((|dcx|+|dcy|)+|dw|)+|dh|
                float cb = ((fabsf(pcx-gx[j])+fabsf(pcy-gy[j]))+fabsf(pw-gw[j]))+fabsf(ph-gh[j]);
                mn[2*j]   = fminf(mn[2*j],   cb);
                float ca = ((fabsf(acx-gx[j])+fabsf(acy-gy[j]))+fabsf(aw-gw[j]))+fabsf(ah-gh[j]);
                mn[2*j+1] = fminf(mn[2*j+1], ca);
            }
        }
    }
#pragma unroll
    for (int l = 0; l < NL; ++l) mnAll[l][tid] = mn[l];
    if (tid < NL) cnt[tid] = 0;
    __syncthreads();

    // ---- threshold reduce: wave w handles list w (8 waves = 8 lists) ----
    {
        int w = tid >> 6, lane = tid & 63;
        const float4* row = (const float4*)&mnAll[w][lane * 8];
        float4 v0 = row[0], v1 = row[1];
        float r[KM] = { INF, INF, INF, INF };
        insf(r, v0.x); insf(r, v0.y); insf(r, v0.z); insf(r, v0.w);
        insf(r, v1.x); insf(r, v1.y); insf(r, v1.z); insf(r, v1.w);
#pragma unroll
        for (int off = 1; off < 64; off <<= 1) {
            float bb[KM];
#pragma unroll
            for (int s = 0; s < KM; ++s) bb[s] = __shfl_xor(r[s], off, 64);
            merge4f(r, bb);
        }
        if (lane == 0) Ts[w] = r[3];   // 4th-smallest of subsample minima
    }
    __syncthreads();

    float T[NL];
#pragma unroll
    for (int l = 0; l < NL; ++l) T[l] = bcast(Ts[l]);   // SGPRs

    // ---- phase B: full scan of the slice, collect keys with cost <= T ----
    for (int it = 0; it < QPT; it += 2) {
        int o0 = it * NT + tid, o1 = (it + 1) * NT + tid;
        float4 p0 = pq[o0], a0 = aq[o0], p1 = pq[o1], a1 = aq[o1];
#pragma unroll
        for (int u = 0; u < 2; ++u) {
            float4 p = u ? p1 : p0;
            float4 a = u ? a1 : a0;
            int qg = qs * QC + (u ? o1 : o0);       // global q, 15 bits
            float pcx=(p.x+p.z)*0.5f, pcy=(p.y+p.w)*0.5f, pw=p.z-p.x, ph=p.w-p.y;
            float acx=(a.x+a.z)*0.5f, acy=(a.y+a.w)*0.5f, aw=a.z-a.x, ah=a.w-a.y;
            float c[NL];
            bool any = false;
#pragma unroll
            for (int j = 0; j < GPB; ++j) {
                c[2*j]   = ((fabsf(pcx-gx[j])+fabsf(pcy-gy[j]))+fabsf(pw-gw[j]))+fabsf(ph-gh[j]);
                c[2*j+1] = ((fabsf(acx-gx[j])+fabsf(acy-gy[j]))+fabsf(aw-gw[j]))+fabsf(ah-gh[j]);
                any = any || (c[2*j] <= T[2*j]) || (c[2*j+1] <= T[2*j+1]);
            }
            if (__any(any)) {                        // rare at wave level
#pragma unroll
                for (int l = 0; l < NL; ++l) {
                    if (c[l] <= T[l]) {
                        int s = atomicAdd(&cnt[l], 1);
                        if (s < BUFCAP)
                            buf[l][s] = (((ull)__float_as_uint(c[l])) << 15)
                                        | (ull)(unsigned)qg;
                    }
                }
            }
        }
    }
    __syncthreads();

    // exact lexicographic top-4 of collected keys -> ws[L][l][0..3]
    if (tid < NL) {
        int l = tid;
        int n = cnt[l]; if (n > BUFCAP) n = BUFCAP;
        ull r[KM] = { ~0ull, ~0ull, ~0ull, ~0ull };
        for (int i = 0; i < n; ++i) ins_u64(r, buf[l][i]);
        ull* w = ws + ((size_t)L * NL + l) * KM;
#pragma unroll
        for (int s = 0; s < KM; ++s) w[s] = r[s];
    }
}

__global__ __launch_bounds__(256) void matcher_merge(
    const ull* __restrict__ ws, int* __restrict__ out)
{
    int t = blockIdx.x * 256 + threadIdx.x;
    if (t >= BSN * 16 * NL) return;          // 2048 tasks
    int b  = t >> 7;           // 0..15
    int gc = (t >> 3) & 15;    // 0..15
    int l  = t & 7;            // 0..7

    ull r[KM];
    {
        int L0 = ((b << 4) | gc) << 2;       // qs = 0
        const ull* w = ws + ((size_t)L0 * NL + l) * KM;
#pragma unroll
        for (int s = 0; s < KM; ++s) r[s] = w[s];
    }
#pragma unroll
    for (int qs = 1; qs < QS; ++qs) {
        int L = (((b << 4) | gc) << 2) | qs;
        const ull* w = ws + ((size_t)L * NL + l) * KM;
#pragma unroll
        for (int s = 0; s < KM; ++s) ins_u64(r, w[s]);
    }

    int gl = l >> 1, type = l & 1;
    int g = gc * GPB + gl;
    int base = b * (2 * KM * GN);
    int* out_j = out + BSN * 2 * KM * GN;
#pragma unroll
    for (int m = 0; m < KM; ++m) {
        int qi = (int)(r[m] & 32767ull);
        // idx_i layout: [b, m, type, g] -> b*512 + m*128 + type*64 + g
        int pos = base + m * (2 * GN) + type * GN + g;
        out[pos]   = qi;
        out_j[pos] = g;
    }
}

// ---- fallback (round-5 proven) if ws is too small ----
__global__ __launch_bounds__(1024) void matcher_single(
    const float4* __restrict__ pred, const float4* __restrict__ anc,
    const float4* __restrict__ gt, int* __restrict__ out)
{
    __shared__ float fws4[8][16][KM];
    __shared__ float fTs[8];
    __shared__ int   fcnt[8];
    __shared__ ull   fbuf[8][64];

    int bid = blockIdx.x;
    int xcd = bid & 7;
    int k   = bid >> 3;
    int b   = (xcd << 1) | (k & 1);
    int gc  = k >> 1;
    int tid = threadIdx.x;

    float gx[4], gy[4], gw[4], gh[4];
#pragma unroll
    for (int j = 0; j < 4; ++j) {
        float4 gb = gt[b * GN + gc * 4 + j];
        gx[j] = (gb.x + gb.z) * 0.5f; gy[j] = (gb.y + gb.w) * 0.5f;
        gw[j] = gb.z - gb.x;          gh[j] = gb.w - gb.y;
    }
    const float4* pb = pred + (size_t)b * QN;
    const float4* ab = anc  + (size_t)b * QN;

    float mn[8];
#pragma unroll
    for (int l = 0; l < 8; ++l) mn[l] = INF;

    for (int q0 = tid; q0 < QN; q0 += 1024) {
        float4 p = pb[q0], a = ab[q0];
        float pcx=(p.x+p.z)*0.5f, pcy=(p.y+p.w)*0.5f, pw=p.z-p.x, ph=p.w-p.y;
        float acx=(a.x+a.z)*0.5f, acy=(a.y+a.w)*0.5f, aw=a.z-a.x, ah=a.w-a.y;
#pragma unroll
        for (int j = 0; j < 4; ++j) {
            mn[2*j]   = fminf(mn[2*j],   ((fabsf(pcx-gx[j])+fabsf(pcy-gy[j]))+fabsf(pw-gw[j]))+fabsf(ph-gh[j]));
            mn[2*j+1] = fminf(mn[2*j+1], ((fabsf(acx-gx[j])+fabsf(acy-gy[j]))+fabsf(aw-gw[j]))+fabsf(ah-gh[j]));
        }
    }

    float m4[8][KM];
#pragma unroll
    for (int l = 0; l < 8; ++l) { m4[l][0]=mn[l]; m4[l][1]=INF; m4[l][2]=INF; m4[l][3]=INF; }
#pragma unroll
    for (int off = 1; off < 64; off <<= 1) {
#pragma unroll
        for (int l = 0; l < 8; ++l) {
            float bb[KM];
#pragma unroll
            for (int s = 0; s < KM; ++s) bb[s] = __shfl_xor(m4[l][s], off, 64);
            merge4f(m4[l], bb);
        }
    }
    int lane = tid & 63, wv = tid >> 6;
    if (lane == 0)
#pragma unroll
        for (int l = 0; l < 8; ++l)
#pragma unroll
            for (int s = 0; s < KM; ++s) fws4[l][wv][s] = m4[l][s];
    if (tid < 8) fcnt[tid] = 0;
    __syncthreads();
    if (tid < 8) {
        float r[KM];
#pragma unroll
        for (int s = 0; s < KM; ++s) r[s] = fws4[tid][0][s];
        for (int w = 1; w < 16; ++w) merge4f(r, fws4[tid][w]);
        fTs[tid] = r[3];
    }
    __syncthreads();
    float T[8];
#pragma unroll
    for (int l = 0; l < 8; ++l) T[l] = fTs[l];

    for (int q0 = tid; q0 < QN; q0 += 1024) {
        float4 p = pb[q0], a = ab[q0];
        float pcx=(p.x+p.z)*0.5f, pcy=(p.y+p.w)*0.5f, pw=p.z-p.x, ph=p.w-p.y;
        float acx=(a.x+a.z)*0.5f, acy=(a.y+a.w)*0.5f, aw=a.z-a.x, ah=a.w-a.y;
#pragma unroll
        for (int j = 0; j < 4; ++j) {
            float cb = ((fabsf(pcx-gx[j])+fabsf(pcy-gy[j]))+fabsf(pw-gw[j]))+fabsf(ph-gh[j]);
            if (cb <= T[2*j]) {
                int s = atomicAdd(&fcnt[2*j], 1);
                if (s < 64) fbuf[2*j][s] = (((ull)__float_as_uint(cb)) << 15) | (ull)(unsigned)q0;
            }
            float ca = ((fabsf(acx-gx[j])+fabsf(acy-gy[j]))+fabsf(aw-gw[j]))+fabsf(ah-gh[j]);
            if (ca <= T[2*j+1]) {
                int s = atomicAdd(&fcnt[2*j+1], 1);
                if (s < 64) fbuf[2*j+1][s] = (((ull)__float_as_uint(ca)) << 15) | (ull)(unsigned)q0;
            }
        }
    }
    __syncthreads();

    if (tid < 8) {
        int l = tid, n = fcnt[l]; if (n > 64) n = 64;
        ull r[KM] = { ~0ull, ~0ull, ~0ull, ~0ull };
        for (int i = 0; i < n; ++i) ins_u64(r, fbuf[l][i]);
        int gl = l >> 1, type = l & 1;
        int g = gc * 4 + gl;
        int base = b * (2 * KM * GN);
        int* out_j = out + BSN * 2 * KM * GN;
#pragma unroll
        for (int m = 0; m < KM; ++m) {
            int qi = (int)(r[m] & 32767ull);
            int pos = base + m * (2 * GN) + type * GN + g;
            out[pos]   = qi;
            out_j[pos] = g;
        }
    }
}

extern "C" void kernel_launch(void* const* d_in, const int* in_sizes, int n_in,
                              void* d_out, int out_size, void* d_ws, size_t ws_size,
                              hipStream_t stream) {
    const float4* pred = (const float4*)d_in[0];
    const float4* anc  = (const float4*)d_in[1];
    const float4* gt   = (const float4*)d_in[2];
    int* out = (int*)d_out;

    if (ws_size >= WS_NEED) {
        ull* ws = (ull*)d_ws;
        matcher_scan<<<NB, NT, 0, stream>>>(pred, anc, gt, ws);
        matcher_merge<<<8, 256, 0, stream>>>(ws, out);
    } else {
        matcher_single<<<256, 1024, 0, stream>>>(pred, anc, gt, out);
    }
}

// Round 9
// 40.665 us; speedup vs baseline: 2.4043x; 1.2543x over previous
//
#include <hip/hip_runtime.h>

typedef unsigned long long ull;

#define QN 32768
#define GN 64
#define BSN 16
#define KM 4
#define INF __builtin_inff()

// ---- main path: 512 blocks x 512 thr, GPB=8 both types, ballot collect ----
#define GPB 8                   // gt boxes per block
#define NL  (GPB * 2)           // 16 lists (pred+anchor)
#define NT  512
#define NW  (NT / 64)           // 8 waves
#define QS  4                   // q-split
#define QC  (QN / QS)           // 8192 q per block
#define QPT (QC / NT)           // 16 q per thread
#define SUB 4                   // subsample iters/thread (1/4 of slice)
#define NB  (BSN * 8 * QS)      // 512 blocks
#define BUFCAP 128
#define WS_NEED ((size_t)NB * NL * KM * sizeof(ull))   // 256 KB (proven available)

__device__ __forceinline__ float bcast(float x) {
    return __uint_as_float(__builtin_amdgcn_readfirstlane(__float_as_uint(x)));
}

// a <- lowest-4 of merge(a,b), both ascending-sorted float[4]. 12 f32 minmax.
__device__ __forceinline__ void merge4f(float* a, const float* b) {
    float m0 = fminf(a[0], b[3]);
    float m1 = fminf(a[1], b[2]);
    float m2 = fminf(a[2], b[1]);
    float m3 = fminf(a[3], b[0]);
    float x0 = fminf(m0, m2), x2 = fmaxf(m0, m2);
    float x1 = fminf(m1, m3), x3 = fmaxf(m1, m3);
    a[0] = fminf(x0, x1); a[1] = fmaxf(x0, x1);
    a[2] = fminf(x2, x3); a[3] = fmaxf(x2, x3);
}

// branchy sorted-insert (ascending r[0..3]), keep 4 smallest values
__device__ __forceinline__ void insf(float* r, float v) {
    if (v < r[3]) {
        r[3] = v; float t;
        if (r[3] < r[2]) { t = r[2]; r[2] = r[3]; r[3] = t; }
        if (r[2] < r[1]) { t = r[1]; r[1] = r[2]; r[2] = t; }
        if (r[1] < r[0]) { t = r[0]; r[0] = r[1]; r[1] = t; }
    }
}

// sorted-insert (ascending r[0..3]) of u64 key, keep 4 smallest
__device__ __forceinline__ void ins_u64(ull* r, ull kk) {
    if (kk < r[3]) {
        r[3] = kk; ull t;
        if (r[3] < r[2]) { t = r[2]; r[2] = r[3]; r[3] = t; }
        if (r[2] < r[1]) { t = r[1]; r[1] = r[2]; r[2] = t; }
        if (r[1] < r[0]) { t = r[0]; r[0] = r[1]; r[1] = t; }
    }
}

// 16 costs (8 gt x {pred,anchor}) for one q, exact reference op order:
// ((|dcx|+|dcy|)+|dw|)+|dh| -- no contractible FMA patterns, bit-stable.
__device__ __forceinline__ void eval16(
    const float* gx, const float* gy, const float* gw, const float* gh,
    float4 p, float4 a, float* c)
{
    float pcx = (p.x + p.z) * 0.5f, pcy = (p.y + p.w) * 0.5f;
    float pw  = p.z - p.x,          ph  = p.w - p.y;
    float acx = (a.x + a.z) * 0.5f, acy = (a.y + a.w) * 0.5f;
    float aw  = a.z - a.x,          ah  = a.w - a.y;
#pragma unroll
    for (int j = 0; j < GPB; ++j) {
        c[2*j]   = ((fabsf(pcx - gx[j]) + fabsf(pcy - gy[j]))
                    + fabsf(pw - gw[j])) + fabsf(ph - gh[j]);
        c[2*j+1] = ((fabsf(acx - gx[j]) + fabsf(acy - gy[j]))
                    + fabsf(aw - gw[j])) + fabsf(ah - gh[j]);
    }
}

__global__ __launch_bounds__(NT, 4) void matcher_scan(
    const float4* __restrict__ pred, const float4* __restrict__ anc,
    const float4* __restrict__ gt, ull* __restrict__ ws)
{
    __shared__ float mnAll[NL][NT];     // 32 KB: per-thread subsample minima
    __shared__ float Ts[NL];
    __shared__ int   cnt[NL];
    __shared__ ull   buf[NL][BUFCAP];   // 16 KB

    // XCD remap (bijective, 512%8==0): 64 consecutive logical blocks per XCD
    // = 2 whole batches (pred+anc = 2 MB) -> fits private 4 MB L2.
    int L   = ((blockIdx.x & 7) << 6) | (blockIdx.x >> 3);
    int b   = L >> 5;             // 0..15
    int gc  = (L >> 2) & 7;       // 0..7 (chunk of 8 gt)
    int qs  = L & 3;              // 0..3
    int tid = threadIdx.x;

    // gt chunk cxcywh -> SGPRs (block-uniform)
    float gx[GPB], gy[GPB], gw[GPB], gh[GPB];
#pragma unroll
    for (int j = 0; j < GPB; ++j) {
        float4 gb = gt[b * GN + gc * GPB + j];
        gx[j] = bcast((gb.x + gb.z) * 0.5f);
        gy[j] = bcast((gb.y + gb.w) * 0.5f);
        gw[j] = bcast(gb.z - gb.x);
        gh[j] = bcast(gb.w - gb.y);
    }

    const float4* pq = pred + (size_t)b * QN + qs * QC;
    const float4* aq = anc  + (size_t)b * QN + qs * QC;

    // ---- phase A (subsample 1/4): per-thread running min per list ----
    // T from a subset >= 4th-smallest of the subset >= v4 of the slice,
    // so phase-B's filter {c <= T} provably contains the true top-4.
    float mn[NL];
#pragma unroll
    for (int l = 0; l < NL; ++l) mn[l] = INF;

#pragma unroll
    for (int it = 0; it < SUB; it += 2) {
        int o0 = it * NT + tid, o1 = o0 + NT;
        float4 p0 = pq[o0], a0 = aq[o0], p1 = pq[o1], a1 = aq[o1];
        float c[NL];
        eval16(gx, gy, gw, gh, p0, a0, c);
#pragma unroll
        for (int l = 0; l < NL; ++l) mn[l] = fminf(mn[l], c[l]);
        eval16(gx, gy, gw, gh, p1, a1, c);
#pragma unroll
        for (int l = 0; l < NL; ++l) mn[l] = fminf(mn[l], c[l]);
    }
#pragma unroll
    for (int l = 0; l < NL; ++l) mnAll[l][tid] = mn[l];
    if (tid < NL) cnt[tid] = 0;
    __syncthreads();

    // ---- threshold reduce: wave w handles lists 2w, 2w+1 ----
    {
        int wv = tid >> 6, lane = tid & 63;
#pragma unroll
        for (int li = 0; li < 2; ++li) {
            int l = wv * 2 + li;
            float r[KM] = { INF, INF, INF, INF };
#pragma unroll
            for (int i = 0; i < 8; ++i) insf(r, mnAll[l][lane + 64 * i]);
#pragma unroll
            for (int off = 1; off < 64; off <<= 1) {
                float bb[KM];
#pragma unroll
                for (int s = 0; s < KM; ++s) bb[s] = __shfl_xor(r[s], off, 64);
                merge4f(r, bb);
            }
            if (lane == 0) Ts[l] = r[3];   // 4th-smallest of subsample minima
        }
    }
    __syncthreads();

    float T[NL];
#pragma unroll
    for (int l = 0; l < NL; ++l) T[l] = bcast(Ts[l]);   // SGPRs

    // ---- phase B: full scan of the slice; per-list ballot-guarded collect ----
    for (int it = 0; it < QPT; it += 2) {
        int o0 = it * NT + tid, o1 = o0 + NT;
        float4 p0 = pq[o0], a0 = aq[o0], p1 = pq[o1], a1 = aq[o1];
#pragma unroll
        for (int u = 0; u < 2; ++u) {
            float4 p = u ? p1 : p0;
            float4 a = u ? a1 : a0;
            int qg = qs * QC + (u ? o1 : o0);        // global q, 15 bits
            float c[NL];
            eval16(gx, gy, gw, gh, p, a, c);
#pragma unroll
            for (int l = 0; l < NL; ++l) {
                // wave-level guard: the v_cmp is needed anyway; branch taken
                // only when some lane qualifies (~10% per list per wave-q)
                if (__ballot(c[l] <= T[l])) {
                    if (c[l] <= T[l]) {
                        int s = atomicAdd(&cnt[l], 1);
                        if (s < BUFCAP)
                            buf[l][s] = (((ull)__float_as_uint(c[l])) << 15)
                                        | (ull)(unsigned)qg;
                    }
                }
            }
        }
    }
    __syncthreads();

    // exact lexicographic top-4 of collected keys -> ws[L][l][0..3]
    if (tid < NL) {
        int l = tid;
        int n = cnt[l]; if (n > BUFCAP) n = BUFCAP;
        ull r[KM] = { ~0ull, ~0ull, ~0ull, ~0ull };
        for (int i = 0; i < n; ++i) ins_u64(r, buf[l][i]);
        ull* w = ws + ((size_t)L * NL + l) * KM;
#pragma unroll
        for (int s = 0; s < KM; ++s) w[s] = r[s];
    }
}

__global__ __launch_bounds__(256) void matcher_merge(
    const ull* __restrict__ ws, int* __restrict__ out)
{
    int t = blockIdx.x * 256 + threadIdx.x;
    if (t >= BSN * 8 * NL) return;           // 2048 tasks
    int b  = t >> 7;           // 0..15
    int gc = (t >> 4) & 7;     // 0..7
    int l  = t & 15;           // 0..15

    ull r[KM];
    {
        int L0 = (b << 5) | (gc << 2);       // qs = 0
        const ull* w = ws + ((size_t)L0 * NL + l) * KM;
#pragma unroll
        for (int s = 0; s < KM; ++s) r[s] = w[s];
    }
#pragma unroll
    for (int qs = 1; qs < QS; ++qs) {
        int L = (b << 5) | (gc << 2) | qs;
        const ull* w = ws + ((size_t)L * NL + l) * KM;
#pragma unroll
        for (int s = 0; s < KM; ++s) ins_u64(r, w[s]);
    }

    int gl = l >> 1, type = l & 1;
    int g = gc * GPB + gl;
    int base = b * (2 * KM * GN);
    int* out_j = out + BSN * 2 * KM * GN;
#pragma unroll
    for (int m = 0; m < KM; ++m) {
        int qi = (int)(r[m] & 32767ull);
        // idx_i layout: [b, m, type, g] -> b*512 + m*128 + type*64 + g
        int pos = base + m * (2 * GN) + type * GN + g;
        out[pos]   = qi;
        out_j[pos] = g;
    }
}

// ---- fallback (round-5 proven) if ws is too small ----
__global__ __launch_bounds__(1024) void matcher_single(
    const float4* __restrict__ pred, const float4* __restrict__ anc,
    const float4* __restrict__ gt, int* __restrict__ out)
{
    __shared__ float fws4[8][16][KM];
    __shared__ float fTs[8];
    __shared__ int   fcnt[8];
    __shared__ ull   fbuf[8][64];

    int bid = blockIdx.x;
    int xcd = bid & 7;
    int k   = bid >> 3;
    int b   = (xcd << 1) | (k & 1);
    int gc  = k >> 1;
    int tid = threadIdx.x;

    float gx[4], gy[4], gw[4], gh[4];
#pragma unroll
    for (int j = 0; j < 4; ++j) {
        float4 gb = gt[b * GN + gc * 4 + j];
        gx[j] = (gb.x + gb.z) * 0.5f; gy[j] = (gb.y + gb.w) * 0.5f;
        gw[j] = gb.z - gb.x;          gh[j] = gb.w - gb.y;
    }
    const float4* pb = pred + (size_t)b * QN;
    const float4* ab = anc  + (size_t)b * QN;

    float mn[8];
#pragma unroll
    for (int l = 0; l < 8; ++l) mn[l] = INF;

    for (int q0 = tid; q0 < QN; q0 += 1024) {
        float4 p = pb[q0], a = ab[q0];
        float pcx=(p.x+p.z)*0.5f, pcy=(p.y+p.w)*0.5f, pw=p.z-p.x, ph=p.w-p.y;
        float acx=(a.x+a.z)*0.5f, acy=(a.y+a.w)*0.5f, aw=a.z-a.x, ah=a.w-a.y;
#pragma unroll
        for (int j = 0; j < 4; ++j) {
            mn[2*j]   = fminf(mn[2*j],   ((fabsf(pcx-gx[j])+fabsf(pcy-gy[j]))+fabsf(pw-gw[j]))+fabsf(ph-gh[j]));
            mn[2*j+1] = fminf(mn[2*j+1], ((fabsf(acx-gx[j])+fabsf(acy-gy[j]))+fabsf(aw-gw[j]))+fabsf(ah-gh[j]));
        }
    }

    float m4[8][KM];
#pragma unroll
    for (int l = 0; l < 8; ++l) { m4[l][0]=mn[l]; m4[l][1]=INF; m4[l][2]=INF; m4[l][3]=INF; }
#pragma unroll
    for (int off = 1; off < 64; off <<= 1) {
#pragma unroll
        for (int l = 0; l < 8; ++l) {
            float bb[KM];
#pragma unroll
            for (int s = 0; s < KM; ++s) bb[s] = __shfl_xor(m4[l][s], off, 64);
            merge4f(m4[l], bb);
        }
    }
    int lane = tid & 63, wv = tid >> 6;
    if (lane == 0)
#pragma unroll
        for (int l = 0; l < 8; ++l)
#pragma unroll
            for (int s = 0; s < KM; ++s) fws4[l][wv][s] = m4[l][s];
    if (tid < 8) fcnt[tid] = 0;
    __syncthreads();
    if (tid < 8) {
        float r[KM];
#pragma unroll
        for (int s = 0; s < KM; ++s) r[s] = fws4[tid][0][s];
        for (int w = 1; w < 16; ++w) merge4f(r, fws4[tid][w]);
        fTs[tid] = r[3];
    }
    __syncthreads();
    float T[8];
#pragma unroll
    for (int l = 0; l < 8; ++l) T[l] = fTs[l];

    for (int q0 = tid; q0 < QN; q0 += 1024) {
        float4 p = pb[q0], a = ab[q0];
        float pcx=(p.x+p.z)*0.5f, pcy=(p.y+p.w)*0.5f, pw=p.z-p.x, ph=p.w-p.y;
        float acx=(a.x+a.z)*0.5f, acy=(a.y+a.w)*0.5f, aw=a.z-a.x, ah=a.w-a.y;
#pragma unroll
        for (int j = 0; j < 4; ++j) {
            float cb = ((fabsf(pcx-gx[j])+fabsf(pcy-gy[j]))+fabsf(pw-gw[j]))+fabsf(ph-gh[j]);
            if (cb <= T[2*j]) {
                int s = atomicAdd(&fcnt[2*j], 1);
                if (s < 64) fbuf[2*j][s] = (((ull)__float_as_uint(cb)) << 15) | (ull)(unsigned)q0;
            }
            float ca = ((fabsf(acx-gx[j])+fabsf(acy-gy[j]))+fabsf(aw-gw[j]))+fabsf(ah-gh[j]);
            if (ca <= T[2*j+1]) {
                int s = atomicAdd(&fcnt[2*j+1], 1);
                if (s < 64) fbuf[2*j+1][s] = (((ull)__float_as_uint(ca)) << 15) | (ull)(unsigned)q0;
            }
        }
    }
    __syncthreads();

    if (tid < 8) {
        int l = tid, n = fcnt[l]; if (n > 64) n = 64;
        ull r[KM] = { ~0ull, ~0ull, ~0ull, ~0ull };
        for (int i = 0; i < n; ++i) ins_u64(r, fbuf[l][i]);
        int gl = l >> 1, type = l & 1;
        int g = gc * 4 + gl;
        int base = b * (2 * KM * GN);
        int* out_j = out + BSN * 2 * KM * GN;
#pragma unroll
        for (int m = 0; m < KM; ++m) {
            int qi = (int)(r[m] & 32767ull);
            int pos = base + m * (2 * GN) + type * GN + g;
            out[pos]   = qi;
            out_j[pos] = g;
        }
    }
}

extern "C" void kernel_launch(void* const* d_in, const int* in_sizes, int n_in,
                              void* d_out, int out_size, void* d_ws, size_t ws_size,
                              hipStream_t stream) {
    const float4* pred = (const float4*)d_in[0];
    const float4* anc  = (const float4*)d_in[1];
    const float4* gt   = (const float4*)d_in[2];
    int* out = (int*)d_out;

    if (ws_size >= WS_NEED) {
        ull* ws = (ull*)d_ws;
        matcher_scan<<<NB, NT, 0, stream>>>(pred, anc, gt, ws);
        matcher_merge<<<8, 256, 0, stream>>>(ws, out);
    } else {
        matcher_single<<<256, 1024, 0, stream>>>(pred, anc, gt, out);
    }
}